// Round 3
// baseline (7356.290 us; speedup 1.0000x reference)
//
#include <hip/hip_runtime.h>
#include <hip/hip_fp16.h>
#include <math.h>

// Problem constants
#define S1 256
#define S2 256
#define S3 128
#define DV 8
#define NK1 30
#define NK2 30
#define NK3 20
#define NPEN (S1*S2)          // 65536 pencils along x3
#define PENC (S3*DV)          // 1024 elements per v pencil (fp16)
#define GPEN (DV*NK3)         // 160 complex per g pencil (fp16 complex)
#define HSLICE (NK2*DV*NK3)   // 4800 complex per x1 slice of h (fp32)

// Workspace layout in float-slots (4 bytes each)
// v: fp16, NPEN*PENC halfs        = 33,554,432 slots (128 MiB)
// g: fp16 complex (__half2), NPEN*GPEN = 10,485,760 slots (40 MiB)
// h: fp32 complex                  =  2,457,600 slots
// f/Rf: fp32 complex               =    288,000 slots each
// tw128/tw256: fp32 complex        =      5,120 / 15,360 slots
// total = 47,094,272 floats = 179.7 MiB
#define OFF_V     0ull
#define SZ_V      ((unsigned long long)NPEN*PENC/2)
#define OFF_G     (OFF_V + SZ_V)
#define SZ_G      ((unsigned long long)NPEN*GPEN)
#define OFF_H     (OFF_G + SZ_G)
#define SZ_H      ((unsigned long long)S1*HSLICE*2)
#define OFF_F     (OFF_H + SZ_H)
#define SZ_F      ((unsigned long long)NK1*HSLICE*2)
#define OFF_RF    (OFF_F + SZ_F)
#define OFF_TW128 (OFF_RF + SZ_F)
#define OFF_TW256 (OFF_TW128 + 2ull*NK3*S3)

__device__ __forceinline__ float gelu_f(float x){
  return 0.5f*x*(1.0f+erff(x*0.70710678118654752440f));
}

// acc += a * t        (t = e^{-i theta}, forward)
__device__ __forceinline__ void cmac_fwd(float& ar, float& ai, float2 a, float2 t){
  ar = fmaf(a.x, t.x, ar); ar = fmaf(-a.y, t.y, ar);
  ai = fmaf(a.x, t.y, ai); ai = fmaf(a.y, t.x, ai);
}
// acc += a * conj(t)  (inverse: e^{+i theta})
__device__ __forceinline__ void cmac_inv(float& ar, float& ai, float2 a, float2 t){
  ar = fmaf(a.x, t.x, ar); ar = fmaf(a.y, t.y, ar);
  ai = fmaf(a.y, t.x, ai); ai = fmaf(-a.x, t.y, ai);
}

// ---------------------------------------------------------------- twiddles
__global__ __launch_bounds__(256) void k_twiddles(float2* __restrict__ tw128,
                                                  float2* __restrict__ tw256){
  int idx = blockIdx.x*256 + threadIdx.x;
  if (idx < NK3*S3){
    int k = idx >> 7, x = idx & 127;
    int m = (k*x) & 127;
    float a = -(float)m * (1.0f/64.0f);   // theta/pi = -2m/128
    float s, c; sincospif(a, &s, &c);
    tw128[idx] = make_float2(c, s);
  }
  int j = idx - NK3*S3;
  if (j >= 0 && j < NK2*S2){
    int k = j >> 8, x = j & 255;
    int m = (k*x) & 255;
    float a = -(float)m * (1.0f/128.0f); // theta/pi = -2m/256
    float s, c; sincospif(a, &s, &c);
    tw256[j] = make_float2(c, s);
  }
}

// ------------------------------------------------- shallow lift + axis-2 DFT
__global__ __launch_bounds__(256) void k_shallow(const float* __restrict__ x,
    const float* __restrict__ sw, const float* __restrict__ sb,
    __half* __restrict__ v, __half2* __restrict__ g,
    const float2* __restrict__ tw128){
  __shared__ float xs[S3];
  __shared__ float vn[PENC];
  __shared__ float wls[DV], bls[DV];
  int pen = blockIdx.x;
  int t = threadIdx.x;
  if (t < S3) xs[t] = x[(size_t)pen*S3 + t];
  else if (t < S3+DV) wls[t-S3] = sw[t-S3];
  else if (t < S3+2*DV) bls[t-S3-DV] = sb[t-S3-DV];
  __syncthreads();
  int i0 = t*4;
  float vals[4];
  #pragma unroll
  for (int j=0;j<4;j++){
    int idx = i0 + j;
    int x3 = idx >> 3, d = idx & 7;
    float val = gelu_f(fmaf(xs[x3], wls[d], bls[d]));
    vn[idx] = val; vals[j] = val;
  }
  union { __half2 h2[2]; uint2 u; } pk;
  pk.h2[0] = __floats2half2_rn(vals[0], vals[1]);
  pk.h2[1] = __floats2half2_rn(vals[2], vals[3]);
  *reinterpret_cast<uint2*>(&v[(size_t)pen*PENC + i0]) = pk.u;
  __syncthreads();
  if (t < GPEN){
    int d = t/NK3, k3 = t%NK3;
    float ar=0.f, ai=0.f;
    for (int x3=0;x3<S3;x3++){
      float val = vn[x3*DV + d];
      float2 tw = tw128[k3*S3 + x3];
      ar = fmaf(val, tw.x, ar);
      ai = fmaf(val, tw.y, ai);
    }
    g[(size_t)pen*GPEN + t] = __floats2half2_rn(ar, ai);
  }
}

// ------------------------------------------------------- axis-1 forward DFT
// h[x1][k2][d][k3] = sum_x2 g[x1,x2][d][k3] * tw256[k2][x2]
__global__ __launch_bounds__(240) void k_stageB(const __half2* __restrict__ g,
    float2* __restrict__ h, const float2* __restrict__ tw256){
  int x1 = blockIdx.x;
  int k3g = blockIdx.y * 5;
  int t = threadIdx.x;              // 240 = 30 k2 * 8 d
  int k2 = t >> 3, d = t & 7;
  float ar[5] = {0,0,0,0,0}, ai[5] = {0,0,0,0,0};
  const float2* twp = &tw256[k2*S2];
  for (int x2=0;x2<S2;x2++){
    const __half2* gp = &g[((size_t)(x1*S2+x2))*GPEN + d*NK3 + k3g];
    float2 tw = twp[x2];
    #pragma unroll
    for (int j=0;j<5;j++){
      float2 gv = __half22float2(gp[j]);
      cmac_fwd(ar[j], ai[j], gv, tw);
    }
  }
  float2* hp = &h[((size_t)(x1*NK2 + k2))*(DV*NK3) + d*NK3 + k3g];
  #pragma unroll
  for (int j=0;j<5;j++) hp[j] = make_float2(ar[j], ai[j]);
}

// ------------------------------------------------------- axis-0 forward DFT
__global__ __launch_bounds__(256) void k_stageC(const float2* __restrict__ h,
    float2* __restrict__ f, const float2* __restrict__ tw256){
  int idx = blockIdx.x*256 + threadIdx.x;
  if (idx >= NK1*HSLICE) return;
  int k1 = idx / HSLICE, r = idx % HSLICE;
  float ar=0.f, ai=0.f;
  const float2* twp = &tw256[k1*S1];
  for (int x1=0;x1<S1;x1++){
    float2 hv = h[(size_t)x1*HSLICE + r];
    cmac_fwd(ar, ai, hv, twp[x1]);
  }
  f[idx] = make_float2(ar, ai);
}

// ------------------------------------------------------------- mode mixing
__global__ __launch_bounds__(256) void k_mix(const float2* __restrict__ f,
    const float* __restrict__ Rr, const float* __restrict__ Ri,
    float2* __restrict__ Rf){
  int idx = blockIdx.x*256 + threadIdx.x;
  if (idx >= NK1*HSLICE) return;
  int k12 = idx / (DV*NK3), r = idx % (DV*NK3);
  int e = r / NK3, k3 = r % NK3;
  const float2* fp  = &f[(size_t)k12*(DV*NK3) + k3];
  const float* rrp = &Rr[((size_t)k12*NK3 + k3)*64 + e];
  const float* rip = &Ri[((size_t)k12*NK3 + k3)*64 + e];
  float ar=0.f, ai=0.f;
  #pragma unroll
  for (int d=0;d<DV;d++){
    float2 fv = fp[d*NK3];
    float wr = rrp[d*DV], wi = rip[d*DV];
    ar = fmaf(fv.x, wr, ar); ar = fmaf(-fv.y, wi, ar);
    ai = fmaf(fv.x, wi, ai); ai = fmaf(fv.y, wr, ai);
  }
  const float sc = 1.1920928955078125e-7f; // 1/(256*256*128)
  Rf[idx] = make_float2(ar*sc, ai*sc);
}

// ------------------------------------------------------- axis-0 inverse DFT
__global__ __launch_bounds__(256) void k_stageCi(const float2* __restrict__ Rf,
    float2* __restrict__ H, const float2* __restrict__ tw256){
  int idx = blockIdx.x*256 + threadIdx.x;   // exactly 256*4800 threads
  int x1 = idx / HSLICE, r = idx % HSLICE;
  float ar=0.f, ai=0.f;
  #pragma unroll
  for (int k1=0;k1<NK1;k1++){
    float2 a = Rf[(size_t)k1*HSLICE + r];
    cmac_inv(ar, ai, a, tw256[k1*S1 + x1]);
  }
  H[idx] = make_float2(ar, ai);
}

// ------------------------------------------------------- axis-1 inverse DFT
__global__ __launch_bounds__(320) void k_stageBi(const float2* __restrict__ H,
    __half2* __restrict__ G, const float2* __restrict__ tw256){
  __shared__ float2 Hs[HSLICE];            // 38.4 KB
  int x1 = blockIdx.x;
  int t = threadIdx.x;                     // 320
  const float* Hf = (const float*)(&H[(size_t)x1*HSLICE]);
  float* Hsf = (float*)Hs;
  for (int i = t; i < HSLICE*2; i += 320) Hsf[i] = Hf[i];
  __syncthreads();
  int grp = t / (DV*NK3), r = t % (DV*NK3);
  for (int x2 = grp; x2 < S2; x2 += 2){
    float ar=0.f, ai=0.f;
    #pragma unroll
    for (int k2=0;k2<NK2;k2++){
      float2 a = Hs[k2*(DV*NK3) + r];
      cmac_inv(ar, ai, a, tw256[k2*S2 + x2]);
    }
    G[((size_t)(x1*S2 + x2))*GPEN + r] = __floats2half2_rn(ar, ai);
  }
}

// --------------------- combine: inverse axis-2 DFT + skip + GELU + next fwd DFT
__global__ __launch_bounds__(256) void k_combine(__half* __restrict__ v,
    __half2* __restrict__ g, const float* __restrict__ w,
    const float2* __restrict__ tw128){
  __shared__ float2 Gs[GPEN];
  __shared__ float vs[S3*9];     // padded stride 9 to avoid bank conflicts
  __shared__ float vn[PENC];
  __shared__ float wsh[64];
  int pen = blockIdx.x;
  int t = threadIdx.x;
  if (t < GPEN) Gs[t] = __half22float2(g[(size_t)pen*GPEN + t]);
  if (t >= 192) wsh[t-192] = w[t-192];
  {
    union { uint2 u; __half2 h2[2]; } lk;
    lk.u = *reinterpret_cast<const uint2*>(&v[(size_t)pen*PENC + t*4]);
    float2 f0 = __half22float2(lk.h2[0]), f1 = __half22float2(lk.h2[1]);
    float tmp[4] = {f0.x, f0.y, f1.x, f1.y};
    #pragma unroll
    for (int j=0;j<4;j++){
      int idx = t*4+j;
      vs[(idx>>3)*9 + (idx&7)] = tmp[j];
    }
  }
  __syncthreads();
  int x3 = t >> 1, e0 = (t & 1)*4;
  float kp[4];
  #pragma unroll
  for (int j=0;j<4;j++) kp[j] = Gs[(e0+j)*NK3].x;   // k3=0: only real part
  for (int k3=1;k3<NK3;k3++){
    float2 tw = tw128[k3*S3 + x3];
    float c2 = 2.0f*tw.x, s2 = 2.0f*tw.y;
    #pragma unroll
    for (int j=0;j<4;j++){
      float2 Gv = Gs[(e0+j)*NK3 + k3];
      kp[j] = fmaf(Gv.x, c2, kp[j]);
      kp[j] = fmaf(Gv.y, s2, kp[j]);    // tw.y = -sin -> +Gi*s
    }
  }
  #pragma unroll
  for (int d=0;d<DV;d++){
    float vv = vs[x3*9+d];
    #pragma unroll
    for (int j=0;j<4;j++) kp[j] = fmaf(vv, wsh[d*DV + e0 + j], kp[j]);
  }
  float vals[4];
  #pragma unroll
  for (int j=0;j<4;j++){ vals[j] = gelu_f(kp[j]); vn[x3*DV+e0+j] = vals[j]; }
  union { __half2 h2[2]; uint2 u; } pk;
  pk.h2[0] = __floats2half2_rn(vals[0], vals[1]);
  pk.h2[1] = __floats2half2_rn(vals[2], vals[3]);
  *reinterpret_cast<uint2*>(&v[(size_t)pen*PENC + x3*DV + e0]) = pk.u;
  __syncthreads();
  if (t < GPEN){
    int d = t/NK3, k3 = t%NK3;
    float ar=0.f, ai=0.f;
    for (int x3i=0;x3i<S3;x3i++){
      float val = vn[x3i*DV + d];
      float2 tw = tw128[k3*S3 + x3i];
      ar = fmaf(val, tw.x, ar);
      ai = fmaf(val, tw.y, ai);
    }
    g[(size_t)pen*GPEN + t] = __floats2half2_rn(ar, ai);
  }
}

// --------------------- final: inverse axis-2 DFT + skip + GELU + projection
__global__ __launch_bounds__(256) void k_final(const __half* __restrict__ v,
    const __half2* __restrict__ G, const float* __restrict__ w,
    const float* __restrict__ pw, const float* __restrict__ pb,
    float* __restrict__ out, const float2* __restrict__ tw128){
  __shared__ float2 Gs[GPEN];
  __shared__ float vs[S3*9];
  __shared__ float vn[PENC];
  __shared__ float wsh[64];
  __shared__ float pws[DV];
  __shared__ float pbs;
  int pen = blockIdx.x;
  int t = threadIdx.x;
  if (t < GPEN) Gs[t] = __half22float2(G[(size_t)pen*GPEN + t]);
  else if (t < GPEN+DV) pws[t-GPEN] = pw[t-GPEN];
  else if (t == GPEN+DV) pbs = pb[0];
  if (t >= 192) wsh[t-192] = w[t-192];
  {
    union { uint2 u; __half2 h2[2]; } lk;
    lk.u = *reinterpret_cast<const uint2*>(&v[(size_t)pen*PENC + t*4]);
    float2 f0 = __half22float2(lk.h2[0]), f1 = __half22float2(lk.h2[1]);
    float tmp[4] = {f0.x, f0.y, f1.x, f1.y};
    #pragma unroll
    for (int j=0;j<4;j++){
      int idx = t*4+j;
      vs[(idx>>3)*9 + (idx&7)] = tmp[j];
    }
  }
  __syncthreads();
  int x3 = t >> 1, e0 = (t & 1)*4;
  float kp[4];
  #pragma unroll
  for (int j=0;j<4;j++) kp[j] = Gs[(e0+j)*NK3].x;
  for (int k3=1;k3<NK3;k3++){
    float2 tw = tw128[k3*S3 + x3];
    float c2 = 2.0f*tw.x, s2 = 2.0f*tw.y;
    #pragma unroll
    for (int j=0;j<4;j++){
      float2 Gv = Gs[(e0+j)*NK3 + k3];
      kp[j] = fmaf(Gv.x, c2, kp[j]);
      kp[j] = fmaf(Gv.y, s2, kp[j]);
    }
  }
  #pragma unroll
  for (int d=0;d<DV;d++){
    float vv = vs[x3*9+d];
    #pragma unroll
    for (int j=0;j<4;j++) kp[j] = fmaf(vv, wsh[d*DV + e0 + j], kp[j]);
  }
  #pragma unroll
  for (int j=0;j<4;j++) vn[x3*DV+e0+j] = gelu_f(kp[j]);
  __syncthreads();
  if (t < S3){
    float acc = pbs;
    #pragma unroll
    for (int e=0;e<DV;e++) acc = fmaf(vn[t*DV+e], pws[e], acc);
    out[(size_t)pen*S3 + t] = acc;
  }
}

extern "C" void kernel_launch(void* const* d_in, const int* in_sizes, int n_in,
                              void* d_out, int out_size, void* d_ws, size_t ws_size,
                              hipStream_t stream){
  const float* x  = (const float*)d_in[0];
  const float* sw = (const float*)d_in[1];
  const float* sb = (const float*)d_in[2];
  const float* Rr[4] = {(const float*)d_in[3],(const float*)d_in[6],(const float*)d_in[9],(const float*)d_in[12]};
  const float* Ri[4] = {(const float*)d_in[4],(const float*)d_in[7],(const float*)d_in[10],(const float*)d_in[13]};
  const float* w[4]  = {(const float*)d_in[5],(const float*)d_in[8],(const float*)d_in[11],(const float*)d_in[14]};
  const float* pw = (const float*)d_in[15];
  const float* pb = (const float*)d_in[16];
  float* out = (float*)d_out;
  float* ws = (float*)d_ws;

  __half*  v    = (__half*)(ws + OFF_V);
  __half2* g    = (__half2*)(ws + OFF_G);
  float2* h     = (float2*)(ws + OFF_H);
  float2* f     = (float2*)(ws + OFF_F);
  float2* Rf    = (float2*)(ws + OFF_RF);
  float2* tw128 = (float2*)(ws + OFF_TW128);
  float2* tw256 = (float2*)(ws + OFF_TW256);

  k_twiddles<<<40, 256, 0, stream>>>(tw128, tw256);
  k_shallow<<<NPEN, 256, 0, stream>>>(x, sw, sb, v, g, tw128);
  for (int L = 0; L < 4; L++){
    k_stageB <<<dim3(S1,4), 240, 0, stream>>>(g, h, tw256);
    k_stageC <<<(NK1*HSLICE + 255)/256, 256, 0, stream>>>(h, f, tw256);
    k_mix    <<<(NK1*HSLICE + 255)/256, 256, 0, stream>>>(f, Rr[L], Ri[L], Rf);
    k_stageCi<<<(S1*HSLICE)/256, 256, 0, stream>>>(Rf, h, tw256);
    k_stageBi<<<S1, 320, 0, stream>>>(h, g, tw256);
    if (L < 3)
      k_combine<<<NPEN, 256, 0, stream>>>(v, g, w[L], tw128);
    else
      k_final<<<NPEN, 256, 0, stream>>>(v, g, w[L], pw, pb, out, tw128);
  }
}

// Round 4
// 4021.338 us; speedup vs baseline: 1.8293x; 1.8293x over previous
//
#include <hip/hip_runtime.h>
#include <hip/hip_fp16.h>
#include <math.h>

// Problem constants
#define S1 256
#define S2 256
#define S3 128
#define DV 8
#define NK1 30
#define NK2 30
#define NK3 20
#define NPEN (S1*S2)          // 65536 pencils along x3
#define PENC (S3*DV)          // 1024 elements per v pencil (fp16)
#define GPEN (DV*NK3)         // 160 complex per g pencil (fp16 complex)
#define HSLICE (NK2*DV*NK3)   // 4800 complex per x1 slice of h (fp32)
#define PB 4                  // pencils per block in combine/shallow/final

// Workspace layout in float-slots (4 bytes each) — total ~180 MiB
#define OFF_V     0ull
#define SZ_V      ((unsigned long long)NPEN*PENC/2)
#define OFF_G     (OFF_V + SZ_V)
#define SZ_G      ((unsigned long long)NPEN*GPEN)
#define OFF_H     (OFF_G + SZ_G)
#define SZ_H      ((unsigned long long)S1*HSLICE*2)
#define OFF_F     (OFF_H + SZ_H)
#define SZ_F      ((unsigned long long)NK1*HSLICE*2)
#define OFF_RF    (OFF_F + SZ_F)
#define OFF_TW128 (OFF_RF + SZ_F)
#define OFF_TW256 (OFF_TW128 + 2ull*NK3*S3)

__device__ __forceinline__ float gelu_f(float x){
  return 0.5f*x*(1.0f+erff(x*0.70710678118654752440f));
}
__device__ __forceinline__ void cmac_fwd(float& ar, float& ai, float2 a, float2 t){
  ar = fmaf(a.x, t.x, ar); ar = fmaf(-a.y, t.y, ar);
  ai = fmaf(a.x, t.y, ai); ai = fmaf(a.y, t.x, ai);
}
__device__ __forceinline__ void cmac_inv(float& ar, float& ai, float2 a, float2 t){
  ar = fmaf(a.x, t.x, ar); ar = fmaf(a.y, t.y, ar);
  ai = fmaf(a.y, t.x, ai); ai = fmaf(-a.x, t.y, ai);
}

// ---------------------------------------------------------------- twiddles
__global__ __launch_bounds__(256) void k_twiddles(float2* __restrict__ tw128,
                                                  float2* __restrict__ tw256){
  int idx = blockIdx.x*256 + threadIdx.x;
  if (idx < NK3*S3){
    int k = idx >> 7, x = idx & 127;
    int m = (k*x) & 127;
    float a = -(float)m * (1.0f/64.0f);
    float s, c; sincospif(a, &s, &c);
    tw128[idx] = make_float2(c, s);   // (cos, -sin)
  }
  int j = idx - NK3*S3;
  if (j >= 0 && j < NK2*S2){
    int k = j >> 8, x = j & 255;
    int m = (k*x) & 255;
    float a = -(float)m * (1.0f/128.0f);
    float s, c; sincospif(a, &s, &c);
    tw256[j] = make_float2(c, s);
  }
}

// =========================================================================
// Shared building blocks for the pencil kernels (4 pencils / 256-thr block)
//   LDS: tws[20][129] fp32 twiddles, vn[PB][8][128] fp32 (d-major!),
//        Gsm[PB][160] float2 (pre-scaled by 2 for k3>0), wsm[64]
// =========================================================================

// phase 2: forward axis-2 DFT from vn (d-major) -> g, lanes 0..39 of each warp
__device__ __forceinline__ void fwd_dft_phase(const float (*vnp)[128],
    const float2* tws, __half2* gout_pen, int l){
  if (l >= 40) return;
  int k3 = l % 20, dg = l / 20;
  float ar[4] = {0,0,0,0}, ai[4] = {0,0,0,0};
  for (int x0 = 0; x0 < 128; x0 += 4){
    float4 vv[4];
    #pragma unroll
    for (int di=0; di<4; di++)
      vv[di] = *reinterpret_cast<const float4*>(&vnp[dg*4+di][x0]);
    float2 t2[4];
    #pragma unroll
    for (int xi=0; xi<4; xi++) t2[xi] = tws[k3*129 + x0 + xi];
    #pragma unroll
    for (int di=0; di<4; di++){
      ar[di] = fmaf(vv[di].x, t2[0].x, ar[di]); ai[di] = fmaf(vv[di].x, t2[0].y, ai[di]);
      ar[di] = fmaf(vv[di].y, t2[1].x, ar[di]); ai[di] = fmaf(vv[di].y, t2[1].y, ai[di]);
      ar[di] = fmaf(vv[di].z, t2[2].x, ar[di]); ai[di] = fmaf(vv[di].z, t2[2].y, ai[di]);
      ar[di] = fmaf(vv[di].w, t2[3].x, ar[di]); ai[di] = fmaf(vv[di].w, t2[3].y, ai[di]);
    }
  }
  #pragma unroll
  for (int di=0; di<4; di++)
    gout_pen[(dg*4+di)*20 + k3] = __floats2half2_rn(ar[di], ai[di]);
}

// store new v (fp16) from vn via LDS transpose, all 256 threads
__device__ __forceinline__ void store_v_phase(const float (*vn)[8][128],
    __half* vout, size_t pen_base, int t){
  #pragma unroll
  for (int it=0; it<2; it++){
    int p2 = it*2 + (t>>7);
    int x3 = t & 127;
    float a[8];
    #pragma unroll
    for (int d=0; d<8; d++) a[d] = vn[p2][d][x3];
    union { uint4 u; __half2 h2[4]; } pk;
    pk.h2[0] = __floats2half2_rn(a[0], a[1]);
    pk.h2[1] = __floats2half2_rn(a[2], a[3]);
    pk.h2[2] = __floats2half2_rn(a[4], a[5]);
    pk.h2[3] = __floats2half2_rn(a[6], a[7]);
    *reinterpret_cast<uint4*>(vout + ((pen_base + p2)<<10) + x3*8) = pk.u;
  }
}

// ------------------------------------------------- shallow lift + axis-2 DFT
__global__ __launch_bounds__(256) void k_shallow(const float* __restrict__ x,
    const float* __restrict__ sw, const float* __restrict__ sb,
    __half* __restrict__ v, __half2* __restrict__ g,
    const float2* __restrict__ twg){
  __shared__ float2 tws[20*129];
  __shared__ float  vn[PB][8][128];
  int t = threadIdx.x;
  size_t pen_base = (size_t)blockIdx.x * PB;
  for (int i=t; i<2560; i+=256){ int k=i>>7, xx=i&127; tws[k*129+xx] = twg[i]; }
  int p = t >> 6, l = t & 63;
  int xb = l & 31, e0 = (l >> 5)*4;
  size_t pen = pen_base + p;
  float swr[4], sbr[4];
  #pragma unroll
  for (int j=0;j<4;j++){ swr[j] = sw[e0+j]; sbr[j] = sb[e0+j]; }
  #pragma unroll
  for (int xi=0; xi<4; xi++){
    int x3 = xb + 32*xi;
    float xv = x[(pen<<7) + x3];
    #pragma unroll
    for (int j=0;j<4;j++)
      vn[p][e0+j][x3] = gelu_f(fmaf(xv, swr[j], sbr[j]));
  }
  __syncthreads();
  store_v_phase(vn, v, pen_base, t);
  fwd_dft_phase(vn[p], tws, g + pen*GPEN, l);
}

// --------------------- combine: inv axis-2 DFT + skip + GELU + next fwd DFT
__global__ __launch_bounds__(256) void k_combine(__half* __restrict__ v,
    __half2* __restrict__ g, const float* __restrict__ w,
    const float2* __restrict__ twg){
  __shared__ float2 tws[20*129];
  __shared__ float  vn[PB][8][128];
  __shared__ float2 Gsm[PB][160];
  __shared__ float  wsm[64];
  int t = threadIdx.x;
  size_t pen_base = (size_t)blockIdx.x * PB;
  for (int i=t; i<2560; i+=256){ int k=i>>7, xx=i&127; tws[k*129+xx] = twg[i]; }
  {
    const __half2* gsrc = g + pen_base*GPEN;
    float2* Gf = &Gsm[0][0];
    for (int i=t; i<PB*160; i+=256){
      float2 gv = __half22float2(gsrc[i]);
      if (i % 20){ gv.x *= 2.0f; gv.y *= 2.0f; }   // irfft factor 2, k3>0
      Gf[i] = gv;
    }
  }
  if (t < 64) wsm[t] = w[t];
  __syncthreads();

  int p = t >> 6, l = t & 63;
  int xb = l & 31, e0 = (l >> 5)*4;
  size_t pen = pen_base + p;
  float wr[8][4];
  #pragma unroll
  for (int d=0; d<8; d++)
    #pragma unroll
    for (int j=0; j<4; j++) wr[d][j] = wsm[d*8 + e0 + j];
  float kp[4][4];
  #pragma unroll
  for (int xi=0; xi<4; xi++)
    #pragma unroll
    for (int j=0; j<4; j++) kp[xi][j] = Gsm[p][(e0+j)*20].x;  // k3=0, weight 1
  for (int k3=1; k3<NK3; k3++){
    float2 c4[4];
    #pragma unroll
    for (int xi=0; xi<4; xi++) c4[xi] = tws[k3*129 + xb + 32*xi];
    float2 gq[4];
    #pragma unroll
    for (int j=0; j<4; j++) gq[j] = Gsm[p][(e0+j)*20 + k3];
    #pragma unroll
    for (int xi=0; xi<4; xi++)
      #pragma unroll
      for (int j=0; j<4; j++){
        kp[xi][j] = fmaf(gq[j].x, c4[xi].x, kp[xi][j]);
        kp[xi][j] = fmaf(gq[j].y, c4[xi].y, kp[xi][j]);
      }
  }
  #pragma unroll
  for (int xi=0; xi<4; xi++){
    int x3 = xb + 32*xi;
    union { uint4 u; __half2 h2[4]; } lk;
    lk.u = *reinterpret_cast<const uint4*>(v + (pen<<10) + x3*8);
    float vv[8];
    #pragma unroll
    for (int q=0; q<4; q++){
      float2 f2 = __half22float2(lk.h2[q]);
      vv[2*q] = f2.x; vv[2*q+1] = f2.y;
    }
    float s[4];
    #pragma unroll
    for (int j=0;j<4;j++) s[j] = kp[xi][j];
    #pragma unroll
    for (int d=0; d<8; d++)
      #pragma unroll
      for (int j=0; j<4; j++) s[j] = fmaf(vv[d], wr[d][j], s[j]);
    #pragma unroll
    for (int j=0;j<4;j++) vn[p][e0+j][x3] = gelu_f(s[j]);
  }
  __syncthreads();
  store_v_phase(vn, v, pen_base, t);
  fwd_dft_phase(vn[p], tws, g + pen*GPEN, l);
}

// --------------------- final: inv axis-2 DFT + skip + GELU + projection
__global__ __launch_bounds__(256) void k_final(const __half* __restrict__ v,
    const __half2* __restrict__ g, const float* __restrict__ w,
    const float* __restrict__ pw, const float* __restrict__ pb,
    float* __restrict__ out, const float2* __restrict__ twg){
  __shared__ float2 tws[20*129];
  __shared__ float  vn[PB][8][128];
  __shared__ float2 Gsm[PB][160];
  __shared__ float  wsm[64];
  int t = threadIdx.x;
  size_t pen_base = (size_t)blockIdx.x * PB;
  for (int i=t; i<2560; i+=256){ int k=i>>7, xx=i&127; tws[k*129+xx] = twg[i]; }
  {
    const __half2* gsrc = g + pen_base*GPEN;
    float2* Gf = &Gsm[0][0];
    for (int i=t; i<PB*160; i+=256){
      float2 gv = __half22float2(gsrc[i]);
      if (i % 20){ gv.x *= 2.0f; gv.y *= 2.0f; }
      Gf[i] = gv;
    }
  }
  if (t < 64) wsm[t] = w[t];
  __syncthreads();

  int p = t >> 6, l = t & 63;
  int xb = l & 31, e0 = (l >> 5)*4;
  size_t pen = pen_base + p;
  float wr[8][4];
  #pragma unroll
  for (int d=0; d<8; d++)
    #pragma unroll
    for (int j=0; j<4; j++) wr[d][j] = wsm[d*8 + e0 + j];
  float kp[4][4];
  #pragma unroll
  for (int xi=0; xi<4; xi++)
    #pragma unroll
    for (int j=0; j<4; j++) kp[xi][j] = Gsm[p][(e0+j)*20].x;
  for (int k3=1; k3<NK3; k3++){
    float2 c4[4];
    #pragma unroll
    for (int xi=0; xi<4; xi++) c4[xi] = tws[k3*129 + xb + 32*xi];
    float2 gq[4];
    #pragma unroll
    for (int j=0; j<4; j++) gq[j] = Gsm[p][(e0+j)*20 + k3];
    #pragma unroll
    for (int xi=0; xi<4; xi++)
      #pragma unroll
      for (int j=0; j<4; j++){
        kp[xi][j] = fmaf(gq[j].x, c4[xi].x, kp[xi][j]);
        kp[xi][j] = fmaf(gq[j].y, c4[xi].y, kp[xi][j]);
      }
  }
  #pragma unroll
  for (int xi=0; xi<4; xi++){
    int x3 = xb + 32*xi;
    union { uint4 u; __half2 h2[4]; } lk;
    lk.u = *reinterpret_cast<const uint4*>(v + (pen<<10) + x3*8);
    float vv[8];
    #pragma unroll
    for (int q=0; q<4; q++){
      float2 f2 = __half22float2(lk.h2[q]);
      vv[2*q] = f2.x; vv[2*q+1] = f2.y;
    }
    float s[4];
    #pragma unroll
    for (int j=0;j<4;j++) s[j] = kp[xi][j];
    #pragma unroll
    for (int d=0; d<8; d++)
      #pragma unroll
      for (int j=0; j<4; j++) s[j] = fmaf(vv[d], wr[d][j], s[j]);
    #pragma unroll
    for (int j=0;j<4;j++) vn[p][e0+j][x3] = gelu_f(s[j]);
  }
  __syncthreads();
  // projection: out[pen][x3] = pb + sum_e vn[e][x3]*pw[e]
  float pwr[8];
  #pragma unroll
  for (int e=0;e<8;e++) pwr[e] = pw[e];
  float pbv = pb[0];
  #pragma unroll
  for (int it=0; it<2; it++){
    int p2 = it*2 + (t>>7);
    int x3 = t & 127;
    float acc = pbv;
    #pragma unroll
    for (int e=0;e<8;e++) acc = fmaf(vn[p2][e][x3], pwr[e], acc);
    out[((pen_base + p2)<<7) + x3] = acc;
  }
}

// ------------------------------------------------------- axis-1 forward DFT
// grid (S1, 2): block handles x1, one k3-half (10 k3 per thread)
__global__ __launch_bounds__(256) void k_stageB(const __half2* __restrict__ g,
    float2* __restrict__ h, const float2* __restrict__ twg){
  __shared__ unsigned int gsm[32*160];   // 32 pencils, raw half2 bits, 20KB
  int x1 = blockIdx.x;
  int k3o = blockIdx.y * 10;
  int t = threadIdx.x;
  int k2 = t >> 3, d = t & 7;            // valid for t<240
  float ar[10], ai[10];
  #pragma unroll
  for (int j=0;j<10;j++){ ar[j]=0.f; ai[j]=0.f; }
  for (int c = 0; c < 8; c++){
    __syncthreads();
    const uint4* src = reinterpret_cast<const uint4*>(g + (size_t)(x1*S2 + c*32)*GPEN);
    uint4* dst = reinterpret_cast<uint4*>(gsm);
    #pragma unroll
    for (int r=0; r<5; r++) dst[r*256 + t] = src[r*256 + t];
    __syncthreads();
    if (t < 240){
      for (int x2l = 0; x2l < 32; x2l++){
        float2 tw = twg[k2*S2 + c*32 + x2l];
        const uint2* q = reinterpret_cast<const uint2*>(&gsm[x2l*160 + d*20 + k3o]);
        #pragma unroll
        for (int jj=0; jj<5; jj++){
          uint2 u = q[jj];
          float2 gv0 = __half22float2(*reinterpret_cast<const __half2*>(&u.x));
          float2 gv1 = __half22float2(*reinterpret_cast<const __half2*>(&u.y));
          cmac_fwd(ar[2*jj],   ai[2*jj],   gv0, tw);
          cmac_fwd(ar[2*jj+1], ai[2*jj+1], gv1, tw);
        }
      }
    }
  }
  if (t < 240){
    float2* hp = h + (size_t)((x1*NK2 + k2)*(DV*NK3) + d*NK3 + k3o);
    #pragma unroll
    for (int j=0;j<10;j++) hp[j] = make_float2(ar[j], ai[j]);
  }
}

// ------------------------------------------------------- axis-0 forward DFT
__global__ __launch_bounds__(256) void k_stageC(const float2* __restrict__ h,
    float2* __restrict__ f, const float2* __restrict__ tw256){
  int idx = blockIdx.x*256 + threadIdx.x;
  if (idx >= NK1*HSLICE) return;
  int k1 = idx / HSLICE, r = idx % HSLICE;
  float ar=0.f, ai=0.f;
  const float2* twp = &tw256[k1*S1];
  for (int x1=0;x1<S1;x1++){
    float2 hv = h[(size_t)x1*HSLICE + r];
    cmac_fwd(ar, ai, hv, twp[x1]);
  }
  f[idx] = make_float2(ar, ai);
}

// ------------------------------------------------------------- mode mixing
__global__ __launch_bounds__(256) void k_mix(const float2* __restrict__ f,
    const float* __restrict__ Rr, const float* __restrict__ Ri,
    float2* __restrict__ Rf){
  int idx = blockIdx.x*256 + threadIdx.x;
  if (idx >= NK1*HSLICE) return;
  int k12 = idx / (DV*NK3), r = idx % (DV*NK3);
  int e = r / NK3, k3 = r % NK3;
  const float2* fp  = &f[(size_t)k12*(DV*NK3) + k3];
  const float* rrp = &Rr[((size_t)k12*NK3 + k3)*64 + e];
  const float* rip = &Ri[((size_t)k12*NK3 + k3)*64 + e];
  float ar=0.f, ai=0.f;
  #pragma unroll
  for (int d=0;d<DV;d++){
    float2 fv = fp[d*NK3];
    float wr = rrp[d*DV], wi = rip[d*DV];
    ar = fmaf(fv.x, wr, ar); ar = fmaf(-fv.y, wi, ar);
    ai = fmaf(fv.x, wi, ai); ai = fmaf(fv.y, wr, ai);
  }
  const float sc = 1.1920928955078125e-7f; // 1/(256*256*128)
  Rf[idx] = make_float2(ar*sc, ai*sc);
}

// ------------------------------------------------------- axis-0 inverse DFT
__global__ __launch_bounds__(256) void k_stageCi(const float2* __restrict__ Rf,
    float2* __restrict__ H, const float2* __restrict__ tw256){
  int idx = blockIdx.x*256 + threadIdx.x;
  int x1 = idx / HSLICE, r = idx % HSLICE;
  float ar=0.f, ai=0.f;
  #pragma unroll
  for (int k1=0;k1<NK1;k1++){
    float2 a = Rf[(size_t)k1*HSLICE + r];
    cmac_inv(ar, ai, a, tw256[k1*S1 + x1]);
  }
  H[idx] = make_float2(ar, ai);
}

// ------------------------------------------------------- axis-1 inverse DFT
// grid (S1, 2): block handles x1, one x2-half
__global__ __launch_bounds__(320) void k_stageBi(const float2* __restrict__ H,
    __half2* __restrict__ G, const float2* __restrict__ tw256){
  __shared__ float2 Hs[HSLICE];            // 38.4 KB
  int x1 = blockIdx.x;
  int t = threadIdx.x;                     // 320
  const float* Hf = (const float*)(&H[(size_t)x1*HSLICE]);
  float* Hsf = (float*)Hs;
  for (int i = t; i < HSLICE*2; i += 320) Hsf[i] = Hf[i];
  __syncthreads();
  int grp = t / (DV*NK3), r = t % (DV*NK3);
  int x2beg = blockIdx.y * 128;
  for (int x2 = x2beg + grp; x2 < x2beg + 128; x2 += 2){
    float ar=0.f, ai=0.f;
    #pragma unroll
    for (int k2=0;k2<NK2;k2++){
      float2 a = Hs[k2*(DV*NK3) + r];
      cmac_inv(ar, ai, a, tw256[k2*S2 + x2]);
    }
    G[((size_t)(x1*S2 + x2))*GPEN + r] = __floats2half2_rn(ar, ai);
  }
}

extern "C" void kernel_launch(void* const* d_in, const int* in_sizes, int n_in,
                              void* d_out, int out_size, void* d_ws, size_t ws_size,
                              hipStream_t stream){
  const float* x  = (const float*)d_in[0];
  const float* sw = (const float*)d_in[1];
  const float* sb = (const float*)d_in[2];
  const float* Rr[4] = {(const float*)d_in[3],(const float*)d_in[6],(const float*)d_in[9],(const float*)d_in[12]};
  const float* Ri[4] = {(const float*)d_in[4],(const float*)d_in[7],(const float*)d_in[10],(const float*)d_in[13]};
  const float* w[4]  = {(const float*)d_in[5],(const float*)d_in[8],(const float*)d_in[11],(const float*)d_in[14]};
  const float* pw = (const float*)d_in[15];
  const float* pb = (const float*)d_in[16];
  float* out = (float*)d_out;
  float* ws = (float*)d_ws;

  __half*  v    = (__half*)(ws + OFF_V);
  __half2* g    = (__half2*)(ws + OFF_G);
  float2* h     = (float2*)(ws + OFF_H);
  float2* f     = (float2*)(ws + OFF_F);
  float2* Rf    = (float2*)(ws + OFF_RF);
  float2* tw128 = (float2*)(ws + OFF_TW128);
  float2* tw256 = (float2*)(ws + OFF_TW256);

  k_twiddles<<<40, 256, 0, stream>>>(tw128, tw256);
  k_shallow<<<NPEN/PB, 256, 0, stream>>>(x, sw, sb, v, g, tw128);
  for (int L = 0; L < 4; L++){
    k_stageB <<<dim3(S1,2), 256, 0, stream>>>(g, h, tw256);
    k_stageC <<<(NK1*HSLICE + 255)/256, 256, 0, stream>>>(h, f, tw256);
    k_mix    <<<(NK1*HSLICE + 255)/256, 256, 0, stream>>>(f, Rr[L], Ri[L], Rf);
    k_stageCi<<<(S1*HSLICE)/256, 256, 0, stream>>>(Rf, h, tw256);
    k_stageBi<<<dim3(S1,2), 320, 0, stream>>>(h, g, tw256);
    if (L < 3)
      k_combine<<<NPEN/PB, 256, 0, stream>>>(v, g, w[L], tw128);
    else
      k_final<<<NPEN/PB, 256, 0, stream>>>(v, g, w[L], pw, pb, out, tw128);
  }
}